// Round 10
// baseline (330.104 us; speedup 1.0000x reference)
//
#include <hip/hip_runtime.h>
#include <hip/hip_bf16.h>

// Problem constants
#define N_    4
#define C_    256
#define PS_   4096      // 64*64 source pixels
#define PO_   16384     // 128*128 output pixels
#define COMP_ 64
#define QCH_  100       // K*K*R*R

typedef unsigned short u16;
typedef __attribute__((ext_vector_type(8))) short short8;   // 8 bf16 = 4 VGPR
typedef __attribute__((ext_vector_type(4))) float f32x4;

__device__ __forceinline__ u16 f2bu(float f) {
    __hip_bfloat16 h = __float2bfloat16(f);
    return __builtin_bit_cast(u16, h);
}
__device__ __forceinline__ float bits2f(unsigned u) {
    union { unsigned i; float f; } v; v.i = u; return v.f;
}

// ---------------------------------------------------------------------------
// Kernel 0 (merged prep):
//  bid<256 : Weff_bf[o][c] = bf16( w_bott[o,:256]@w_conv2 + w_bott[o,256+c] ), beff
//  bid<544 : Wb[128 q][576 u] bf16 (pad q 100->128)
//  else    : Wcc_bf[64 m][256 c] bf16
__global__ __launch_bounds__(256) void k_prep(const float* __restrict__ w_bott,
        const float* __restrict__ w_conv2, const float* __restrict__ b_conv2,
        const float* __restrict__ w_ce, const float* __restrict__ w_cc,
        u16* __restrict__ Weff_bf, float* __restrict__ beff,
        u16* __restrict__ Wb, u16* __restrict__ Wcc_bf) {
    int bid = blockIdx.x;
    if (bid < 256) {
        int o = bid, c = threadIdx.x;
        __shared__ float wb[512];
        wb[c]       = w_bott[o * 512 + c];
        wb[c + 256] = w_bott[o * 512 + 256 + c];
        __syncthreads();
        float acc = wb[256 + c];
        #pragma unroll 8
        for (int m = 0; m < 256; ++m)
            acc += wb[m] * w_conv2[m * 256 + c];
        Weff_bf[o * 256 + c] = f2bu(acc);
        if (c == 0) {
            float be = 0.f;
            for (int m = 0; m < 256; ++m) be += wb[m] * b_conv2[m];
            beff[o] = be;
        }
    } else if (bid < 544) {
        int i = (bid - 256) * 256 + threadIdx.x;   // over 128*576
        int q = i / 576, u = i - q * 576;
        float v = (q < 100) ? w_ce[q * 576 + u] : 0.f;
        Wb[i] = f2bu(v);
    } else {
        int j = (bid - 544) * 256 + threadIdx.x;   // over 64*256
        Wcc_bf[j] = f2bu(w_cc[j]);
    }
}

// ---------------------------------------------------------------------------
// Kernel 1 (fused Y GEMM + channel compressor): shares the B (high) staging.
// grid (128 px-blocks, 2 o-halves) — round-6 proven config.
__global__ __launch_bounds__(256) void k_ygemm_fused(const u16* __restrict__ Weff_bf,
        const u16* __restrict__ Wcc_bf, const float* __restrict__ high,
        const float* __restrict__ b_cc, u16* __restrict__ Yt,
        float* __restrict__ comp) {
    int tid = threadIdx.x;
    int wid = tid >> 6, lane = tid & 63;
    int col = lane & 15, quad = lane >> 4;
    int px0 = blockIdx.x * 128;
    int y = blockIdx.y;
    int o0 = y * 128;
    int n = px0 >> 12, pxb = px0 & 4095;
    __shared__ u16 As[128 * 40];
    __shared__ u16 As2[32 * 40];
    __shared__ u16 Bs[128 * 40];
    f32x4 acc[2][8] = {};
    f32x4 cacc[8] = {};
    #pragma unroll 1
    for (int k0 = 0; k0 < 256; k0 += 32) {
        __syncthreads();
        #pragma unroll
        for (int it = 0; it < 2; ++it) {
            int s = tid + it * 256;
            int row = s >> 2, seg = s & 3;
            short8 av = *reinterpret_cast<const short8*>(Weff_bf + (o0 + row) * 256 + k0 + seg * 8);
            *reinterpret_cast<short8*>(&As[row * 40 + seg * 8]) = av;
        }
        if (tid < 128) {   // comp weights: 32 rows
            int row = tid >> 2, seg = tid & 3;
            short8 av = *reinterpret_cast<const short8*>(Wcc_bf + (y * 32 + row) * 256 + k0 + seg * 8);
            *reinterpret_cast<short8*>(&As2[row * 40 + seg * 8]) = av;
        }
        #pragma unroll
        for (int it = 0; it < 8; ++it) {
            int idx = it * 256 + tid;           // 0..2047
            int c = (idx >> 7) * 2, px = idx & 127;
            const float* hp = high + (n * C_ + k0 + c) * PS_ + pxb + px;
            unsigned lo = f2bu(hp[0]);
            unsigned hi = f2bu(hp[PS_]);
            *reinterpret_cast<unsigned*>(&Bs[px * 40 + c]) = lo | (hi << 16);
        }
        __syncthreads();
        short8 a0 = *reinterpret_cast<const short8*>(&As[(wid * 32 + col) * 40 + quad * 8]);
        short8 a1 = *reinterpret_cast<const short8*>(&As[(wid * 32 + 16 + col) * 40 + quad * 8]);
        short8 a2;
        if (wid < 2)
            a2 = *reinterpret_cast<const short8*>(&As2[(wid * 16 + col) * 40 + quad * 8]);
        #pragma unroll
        for (int nt = 0; nt < 8; ++nt) {
            short8 b = *reinterpret_cast<const short8*>(&Bs[(nt * 16 + col) * 40 + quad * 8]);
            acc[0][nt] = __builtin_amdgcn_mfma_f32_16x16x32_bf16(a0, b, acc[0][nt], 0, 0, 0);
            acc[1][nt] = __builtin_amdgcn_mfma_f32_16x16x32_bf16(a1, b, acc[1][nt], 0, 0, 0);
            if (wid < 2)
                cacc[nt] = __builtin_amdgcn_mfma_f32_16x16x32_bf16(a2, b, cacc[nt], 0, 0, 0);
        }
    }
    #pragma unroll
    for (int mi = 0; mi < 2; ++mi) {
        int ob = o0 + wid * 32 + mi * 16 + quad * 4;
        #pragma unroll
        for (int nt = 0; nt < 8; ++nt) {
            int gpx = px0 + nt * 16 + col;
            unsigned lo = f2bu(acc[mi][nt][0]) | ((unsigned)f2bu(acc[mi][nt][1]) << 16);
            unsigned hi = f2bu(acc[mi][nt][2]) | ((unsigned)f2bu(acc[mi][nt][3]) << 16);
            uint2 pk; pk.x = lo; pk.y = hi;
            *reinterpret_cast<uint2*>(Yt + (size_t)gpx * 256 + ob) = pk;
        }
    }
    if (wid < 2) {
        #pragma unroll
        for (int r = 0; r < 4; ++r) {
            int m = y * 32 + wid * 16 + quad * 4 + r;
            float bias = b_cc[m];
            float* cp = comp + (size_t)(n * COMP_ + m) * PS_ + pxb + col;
            #pragma unroll
            for (int nt = 0; nt < 8; ++nt)
                cp[nt * 16] = cacc[nt][r] + bias;
        }
    }
}

// ---------------------------------------------------------------------------
// Kernel 2: im2col of comp -> Icol[gpx][576 u] bf16, zero-padded 3x3 (r6 cfg)
__global__ __launch_bounds__(256) void k_im2col(const float* __restrict__ comp,
        u16* __restrict__ Icol) {
    int b = blockIdx.x;
    int n = b >> 6, tile = b & 63;
    int ty0 = (tile >> 3) << 3, tx0 = (tile & 7) << 3;
    int tid = threadIdx.x;
    __shared__ float ct[64 * 100];   // 64 ch x 10x10 halo tile
    for (int idx = tid; idx < 6400; idx += 256) {
        int cc = idx / 100, r = idx - cc * 100;
        int yy = ty0 - 1 + r / 10, xx = tx0 - 1 + (r % 10);
        float v = 0.f;
        if ((unsigned)yy < 64u && (unsigned)xx < 64u)
            v = comp[(n * COMP_ + cc) * PS_ + yy * 64 + xx];
        ct[idx] = v;
    }
    __syncthreads();
    int u0 = tid * 2, u1 = u0 + 1;
    int c0 = (unsigned)u0 / 9u, t0 = u0 - c0 * 9;
    int c1 = (unsigned)u1 / 9u, t1 = u1 - c1 * 9;
    int off0 = c0 * 100 + (t0 / 3) * 10 + (t0 % 3);
    int off1 = c1 * 100 + (t1 / 3) * 10 + (t1 % 3);
    int u2 = 512 + tid * 2, u3 = u2 + 1;   // only tid<32
    int c2 = (unsigned)u2 / 9u, t2 = u2 - c2 * 9;
    int c3 = (unsigned)u3 / 9u, t3 = u3 - c3 * 9;
    int off2 = c2 * 100 + (t2 / 3) * 10 + (t2 % 3);
    int off3 = c3 * 100 + (t3 / 3) * 10 + (t3 % 3);
    #pragma unroll 1
    for (int px = 0; px < 64; ++px) {
        int py = px >> 3, pxx = px & 7;
        int base = py * 10 + pxx;
        int gpx = n * PS_ + (ty0 + py) * 64 + tx0 + pxx;
        u16* dst = Icol + (size_t)gpx * 576;
        unsigned lo = f2bu(ct[off0 + base]);
        unsigned hi = f2bu(ct[off1 + base]);
        *reinterpret_cast<unsigned*>(dst + u0) = lo | (hi << 16);
        if (tid < 32) {
            unsigned lo2 = f2bu(ct[off2 + base]);
            unsigned hi2 = f2bu(ct[off3 + base]);
            *reinterpret_cast<unsigned*>(dst + u2) = lo2 | (hi2 << 16);
        }
    }
}

// ---------------------------------------------------------------------------
// Kernel 3: encoder MFMA GEMM + fused softmax (r6 cfg, 256 blocks, N=64).
// Output msm PLANAR: msm[n][q][4096 px] f32, pre-softmaxed.
__global__ __launch_bounds__(256) void k_encode_mfma(const u16* __restrict__ Wb,
        const u16* __restrict__ Icol, const float* __restrict__ b_ce,
        float* __restrict__ msm) {
    int tid = threadIdx.x;
    int wid = tid >> 6, lane = tid & 63;
    int col = lane & 15, quad = lane >> 4;
    int px0 = blockIdx.x * 64;
    int n = px0 >> 12, pxb = px0 & 4095;
    __shared__ u16 As[128 * 40];
    __shared__ u16 Bs[64 * 40];
    __shared__ float mt[100 * 64];   // [q][px] raw mask values
    f32x4 acc[2][4] = {};
    #pragma unroll 1
    for (int k0 = 0; k0 < 576; k0 += 32) {
        __syncthreads();
        #pragma unroll
        for (int it = 0; it < 2; ++it) {   // A: 128 rows x 4 segs
            int s = tid + it * 256;
            int row = s >> 2, seg = s & 3;
            short8 av = *reinterpret_cast<const short8*>(Wb + row * 576 + k0 + seg * 8);
            *reinterpret_cast<short8*>(&As[row * 40 + seg * 8]) = av;
        }
        {   // B: 64 rows x 4 segs
            int row = tid >> 2, seg = tid & 3;
            short8 bv = *reinterpret_cast<const short8*>(Icol + (size_t)(px0 + row) * 576 + k0 + seg * 8);
            *reinterpret_cast<short8*>(&Bs[row * 40 + seg * 8]) = bv;
        }
        __syncthreads();
        short8 a0 = *reinterpret_cast<const short8*>(&As[(wid * 32 + col) * 40 + quad * 8]);
        short8 a1 = *reinterpret_cast<const short8*>(&As[(wid * 32 + 16 + col) * 40 + quad * 8]);
        #pragma unroll
        for (int nt = 0; nt < 4; ++nt) {
            short8 b = *reinterpret_cast<const short8*>(&Bs[(nt * 16 + col) * 40 + quad * 8]);
            acc[0][nt] = __builtin_amdgcn_mfma_f32_16x16x32_bf16(a0, b, acc[0][nt], 0, 0, 0);
            acc[1][nt] = __builtin_amdgcn_mfma_f32_16x16x32_bf16(a1, b, acc[1][nt], 0, 0, 0);
        }
    }
    // stage raw mask to LDS
    #pragma unroll
    for (int mi = 0; mi < 2; ++mi) {
        int qbase = (wid * 2 + mi) * 16 + quad * 4;
        #pragma unroll
        for (int r = 0; r < 4; ++r) {
            int q = qbase + r;
            if (q < 100) {
                float bias = b_ce[q];
                #pragma unroll
                for (int nt = 0; nt < 4; ++nt)
                    mt[q * 64 + nt * 16 + col] = acc[mi][nt][r] + bias;
            }
        }
    }
    __syncthreads();
    // softmax over 25 taps for (px, sp); write planar q = k*4+sp
    {
        int px = tid & 63, sp = tid >> 6;
        float p[25];
        float mx = -1e30f;
        #pragma unroll
        for (int k = 0; k < 25; ++k) {
            p[k] = mt[(k * 4 + sp) * 64 + px];
            mx = fmaxf(mx, p[k]);
        }
        float sum = 0.f;
        #pragma unroll
        for (int k = 0; k < 25; ++k) { p[k] = __expf(p[k] - mx); sum += p[k]; }
        float inv = 1.f / sum;
        float* mo = msm + ((size_t)n * QCH_ + sp) * PS_ + pxb + px;
        #pragma unroll
        for (int k = 0; k < 25; ++k)
            mo[(size_t)k * 4 * PS_] = p[k] * inv;
    }
}

// ---------------------------------------------------------------------------
// Kernel 4 v9 (= v8 structure): CARAFE reassembly. SAME 512-block grid +
// global access pattern as r0/r6 (proven 31.5 MB fetch), 512 threads/block:
// thread = (px 64, sg y-subpixel 2, chg 32-ch group 4). vs[2][25].
// LDS: mask buffer (25.6 KB) unioned with full-half halo (38 KB).
__global__ __launch_bounds__(512, 4) void k_carafe(const u16* __restrict__ Yt,
        const float* __restrict__ msm, const float* __restrict__ beff,
        float* __restrict__ xout, float* __restrict__ ps, float* __restrict__ pq) {
    int tile = blockIdx.x, n = blockIdx.y, half = blockIdx.z;
    int sh0 = (tile >> 3) << 3, sw0 = (tile & 7) << 3;
    int tid = threadIdx.x;
    int px = tid & 63, g = tid >> 6;       // g 0..7
    int sg = g >> 2;                        // y-subpixel 0/1
    int chg = g & 3;                        // 32-ch group within half
    int ly = px >> 3, lx = px & 7;
    int h = sh0 + ly, w = sw0 + lx;

    __shared__ __align__(16) char smem[144 * 132 * 2];   // 38016 B
    float* mt = reinterpret_cast<float*>(smem);          // first 25600 B
    u16* xt = reinterpret_cast<u16*>(smem);              // [144 px][132 ch-pad]

    // stage pre-softmaxed mask [100 q][64 px] (identical global pattern to r6)
    for (int idx = tid; idx < 6400; idx += 512) {
        int q = idx >> 6, p = idx & 63;
        mt[idx] = msm[((size_t)n * QCH_ + q) * PS_ + (sh0 + (p >> 3)) * 64 + sw0 + (p & 7)];
    }
    __syncthreads();
    float vs[2][25];
    #pragma unroll
    for (int j = 0; j < 2; ++j) {
        #pragma unroll
        for (int k = 0; k < 25; ++k)
            vs[j][k] = mt[(k * 4 + sg * 2 + j) * 64 + px];
    }
    __syncthreads();   // mask buffer dead; reuse as xt

    // stage Yt halo: 12x12 px x 128 ch (this half), 16B/thread pieces
    const u16* Yb = Yt + (size_t)n * PS_ * 256 + half * 128;
    for (int idx = tid; idx < 2304; idx += 512) {
        int sp = idx >> 4, seg = idx & 15;
        int row = sp / 12, colm = sp - row * 12;
        int yy = sh0 - 2 + row, xx = sw0 - 2 + colm;
        short8 val = {};
        if ((unsigned)yy < 64u && (unsigned)xx < 64u)
            val = *reinterpret_cast<const short8*>(Yb + (size_t)(yy * 64 + xx) * 256 + seg * 8);
        *reinterpret_cast<short8*>(&xt[sp * 132 + seg * 8]) = val;
    }
    __syncthreads();

    const u16* bp = xt + (ly * 12 + lx) * 132 + chg * 32;
    float* hp_base = xout + (size_t)(n * C_) * PO_;
    int row_off = (2 * h + sg) * 128 + 2 * w;
    int srow = ((n * 64 + tile) * 2 + half) * 2 + sg;    // 0..2047

    #pragma unroll 1
    for (int cq = 0; cq < 8; ++cq) {
        int c = chg * 32 + cq * 4;          // within half
        int ch = half * 128 + c;
        f32x4 bv = *reinterpret_cast<const f32x4*>(beff + ch);
        float a0[4] = {bv[0], bv[1], bv[2], bv[3]};
        float a1[4] = {bv[0], bv[1], bv[2], bv[3]};
        const u16* tp = bp + cq * 4;
        #pragma unroll
        for (int ky = 0; ky < 5; ++ky) {
            #pragma unroll
            for (int kx = 0; kx < 5; ++kx) {
                uint2 rv = *reinterpret_cast<const uint2*>(tp + (ky * 12 + kx) * 132);
                float f0 = bits2f(rv.x << 16);
                float f1 = bits2f(rv.x & 0xffff0000u);
                float f2 = bits2f(rv.y << 16);
                float f3 = bits2f(rv.y & 0xffff0000u);
                int k = ky * 5 + kx;
                float m0 = vs[0][k], m1 = vs[1][k];
                a0[0] += m0 * f0; a0[1] += m0 * f1;
                a0[2] += m0 * f2; a0[3] += m0 * f3;
                a1[0] += m1 * f0; a1[1] += m1 * f1;
                a1[2] += m1 * f2; a1[3] += m1 * f3;
            }
        }
        // write row (2h+sg), cols 2w..2w+1 per channel
        #pragma unroll
        for (int i = 0; i < 4; ++i) {
            float2 r; r.x = a0[i]; r.y = a1[i];
            *reinterpret_cast<float2*>(hp_base + (size_t)(ch + i) * PO_ + row_off) = r;
        }
        // BN partials: wave-reduce over 64 px (sg,chg uniform per wave)
        f32x4 sv, qv;
        #pragma unroll
        for (int i = 0; i < 4; ++i) {
            float s  = a0[i] + a1[i];
            float q2 = a0[i] * a0[i] + a1[i] * a1[i];
            #pragma unroll
            for (int off = 1; off < 64; off <<= 1) {
                s  += __shfl_xor(s, off);
                q2 += __shfl_xor(q2, off);
            }
            sv[i] = s; qv[i] = q2;
        }
        if (px == 0) {
            *reinterpret_cast<f32x4*>(ps + (size_t)srow * 128 + c) = sv;
            *reinterpret_cast<f32x4*>(pq + (size_t)srow * 128 + c) = qv;
        }
    }
}

// ---------------------------------------------------------------------------
// Kernel 5 (merged stats+norm): block = (channel o, batch n).
// FIX vs round 8: sum partials over ALL batches (512 srows per half), not
// just this block's n — BN uses full-batch statistics.
__global__ __launch_bounds__(256) void k_bn(const float* __restrict__ ps,
        const float* __restrict__ pq, const float* __restrict__ gamma,
        const float* __restrict__ beta, float* __restrict__ xb) {
    int o = blockIdx.x >> 2, n = blockIdx.x & 3;
    int half = o >> 7, coff = o & 127;
    int tid = threadIdx.x;
    // slot = tid covers all (n,tile) pairs [0,256); sum both sg rows.
    int base = (tid * 2 + half) * 2;
    float s = ps[(size_t)(base + 0) * 128 + coff] + ps[(size_t)(base + 1) * 128 + coff];
    float q = pq[(size_t)(base + 0) * 128 + coff] + pq[(size_t)(base + 1) * 128 + coff];
    __shared__ float rs[256], rq[256];
    rs[tid] = s; rq[tid] = q;
    __syncthreads();
    for (int off = 128; off > 0; off >>= 1) {
        if (tid < off) { rs[tid] += rs[tid + off]; rq[tid] += rq[tid + off]; }
        __syncthreads();
    }
    __shared__ float sc_s, sh_s;
    if (tid == 0) {
        float mean = rs[0] * (1.f / 65536.f);
        float var  = rq[0] * (1.f / 65536.f) - mean * mean;
        float sc = rsqrtf(var + 1e-5f) * gamma[o];
        sc_s = sc;
        sh_s = beta[o] - mean * sc;
    }
    __syncthreads();
    float sc = sc_s, sh = sh_s;
    float* p = xb + (size_t)(n * C_ + o) * PO_;
    #pragma unroll 4
    for (int i = tid * 4; i < PO_; i += 1024) {
        float4 v = *reinterpret_cast<const float4*>(p + i);
        v.x = fmaxf(v.x * sc + sh, 0.f);
        v.y = fmaxf(v.y * sc + sh, 0.f);
        v.z = fmaxf(v.z * sc + sh, 0.f);
        v.w = fmaxf(v.w * sc + sh, 0.f);
        *reinterpret_cast<float4*>(p + i) = v;
    }
}

// ---------------------------------------------------------------------------
extern "C" void kernel_launch(void* const* d_in, const int* in_sizes, int n_in,
                              void* d_out, int out_size, void* d_ws, size_t ws_size,
                              hipStream_t stream) {
    const float* high    = (const float*)d_in[1];
    const float* w_cc    = (const float*)d_in[2];
    const float* b_cc    = (const float*)d_in[3];
    const float* w_ce    = (const float*)d_in[4];
    const float* b_ce    = (const float*)d_in[5];
    const float* w_conv2 = (const float*)d_in[6];
    const float* b_conv2 = (const float*)d_in[7];
    const float* w_bott  = (const float*)d_in[8];
    const float* gamma   = (const float*)d_in[9];
    const float* beta    = (const float*)d_in[10];

    char* ws = (char*)d_ws;
    float* beff    = (float*)(ws + 0);
    u16*   Weff_bf = (u16*)  (ws + 3072);        // 131072 B
    u16*   Wcc_bf  = (u16*)  (ws + 134144);      // 32768 B
    u16*   Wb      = (u16*)  (ws + 166912);      // 147456 B -> ends 314368
    float* comp    = (float*)(ws + 314368);      // 4 MB -> ends 4508672
    float* msm     = (float*)(ws + 4508672);     // 6.55 MB pre-softmaxed planar mask
    u16*   Yt      = (u16*)  (ws + 11062272);    // 8.4 MB bf16 -> ends 19450880
    // ps/pq live AFTER Yt (comp region is NOT free: carafe runs after encode,
    // but ps/pq are written by carafe while comp is indeed dead -- keep them
    // in the dedicated region after Yt to be safe):
    float* ps      = (float*)(ws + 19450880);    // 1 MB [2048 srow][128 ch]
    float* pq      = (float*)(ws + 20499456);    // 1 MB -> ends 21548032
    u16*   Icol    = (u16*)  d_out;              // 18.9 MB scratch in d_out (dead before carafe)
    float* xout    = (float*)d_out;              // pre-BN x, normalized in place

    k_prep        <<<608, 256, 0, stream>>>(w_bott, w_conv2, b_conv2, w_ce, w_cc,
                                            Weff_bf, beff, Wb, Wcc_bf);
    k_ygemm_fused <<<dim3(128, 2), 256, 0, stream>>>(Weff_bf, Wcc_bf, high, b_cc, Yt, comp);
    k_im2col      <<<256, 256, 0, stream>>>(comp, Icol);
    k_encode_mfma <<<256, 256, 0, stream>>>(Wb, Icol, b_ce, msm);
    k_carafe      <<<dim3(64, 4, 2), 512, 0, stream>>>(Yt, msm, beff, xout, ps, pq);
    k_bn          <<<1024, 256, 0, stream>>>(ps, pq, gamma, beta, xout);
}

// Round 13
// 247.840 us; speedup vs baseline: 1.3319x; 1.3319x over previous
//
#include <hip/hip_runtime.h>
#include <hip/hip_bf16.h>

// Problem constants
#define N_    4
#define C_    256
#define PS_   4096      // 64*64 source pixels
#define PO_   16384     // 128*128 output pixels
#define COMP_ 64
#define QCH_  100       // K*K*R*R

typedef unsigned short u16;
typedef __attribute__((ext_vector_type(8))) short short8;   // 8 bf16 = 4 VGPR
typedef __attribute__((ext_vector_type(4))) float f32x4;

__device__ __forceinline__ u16 f2bu(float f) {
    __hip_bfloat16 h = __float2bfloat16(f);
    return __builtin_bit_cast(u16, h);
}
__device__ __forceinline__ float bits2f(unsigned u) {
    union { unsigned i; float f; } v; v.i = u; return v.f;
}

// ---------------------------------------------------------------------------
// Kernel 0 (merged prep):
//  bid<256 : Weff_bf[o][c] = bf16( w_bott[o,:256]@w_conv2 + w_bott[o,256+c] ), beff
//  bid<544 : Wb[128 q][576 u] bf16 (pad q 100->128)
//  else    : Wcc_bf[64 m][256 c] bf16
__global__ __launch_bounds__(256) void k_prep(const float* __restrict__ w_bott,
        const float* __restrict__ w_conv2, const float* __restrict__ b_conv2,
        const float* __restrict__ w_ce, const float* __restrict__ w_cc,
        u16* __restrict__ Weff_bf, float* __restrict__ beff,
        u16* __restrict__ Wb, u16* __restrict__ Wcc_bf) {
    int bid = blockIdx.x;
    if (bid < 256) {
        int o = bid, c = threadIdx.x;
        __shared__ float wb[512];
        wb[c]       = w_bott[o * 512 + c];
        wb[c + 256] = w_bott[o * 512 + 256 + c];
        __syncthreads();
        float acc = wb[256 + c];
        #pragma unroll 8
        for (int m = 0; m < 256; ++m)
            acc += wb[m] * w_conv2[m * 256 + c];
        Weff_bf[o * 256 + c] = f2bu(acc);
        if (c == 0) {
            float be = 0.f;
            for (int m = 0; m < 256; ++m) be += wb[m] * b_conv2[m];
            beff[o] = be;
        }
    } else if (bid < 544) {
        int i = (bid - 256) * 256 + threadIdx.x;   // over 128*576
        int q = i / 576, u = i - q * 576;
        float v = (q < 100) ? w_ce[q * 576 + u] : 0.f;
        Wb[i] = f2bu(v);
    } else {
        int j = (bid - 544) * 256 + threadIdx.x;   // over 64*256
        Wcc_bf[j] = f2bu(w_cc[j]);
    }
}

// ---------------------------------------------------------------------------
// Kernel 1 (fused Y GEMM + channel compressor): shares the B (high) staging.
// grid (128 px-blocks, 2 o-halves) — round-6 proven config.
__global__ __launch_bounds__(256) void k_ygemm_fused(const u16* __restrict__ Weff_bf,
        const u16* __restrict__ Wcc_bf, const float* __restrict__ high,
        const float* __restrict__ b_cc, u16* __restrict__ Yt,
        float* __restrict__ comp) {
    int tid = threadIdx.x;
    int wid = tid >> 6, lane = tid & 63;
    int col = lane & 15, quad = lane >> 4;
    int px0 = blockIdx.x * 128;
    int y = blockIdx.y;
    int o0 = y * 128;
    int n = px0 >> 12, pxb = px0 & 4095;
    __shared__ u16 As[128 * 40];
    __shared__ u16 As2[32 * 40];
    __shared__ u16 Bs[128 * 40];
    f32x4 acc[2][8] = {};
    f32x4 cacc[8] = {};
    #pragma unroll 1
    for (int k0 = 0; k0 < 256; k0 += 32) {
        __syncthreads();
        #pragma unroll
        for (int it = 0; it < 2; ++it) {
            int s = tid + it * 256;
            int row = s >> 2, seg = s & 3;
            short8 av = *reinterpret_cast<const short8*>(Weff_bf + (o0 + row) * 256 + k0 + seg * 8);
            *reinterpret_cast<short8*>(&As[row * 40 + seg * 8]) = av;
        }
        if (tid < 128) {   // comp weights: 32 rows
            int row = tid >> 2, seg = tid & 3;
            short8 av = *reinterpret_cast<const short8*>(Wcc_bf + (y * 32 + row) * 256 + k0 + seg * 8);
            *reinterpret_cast<short8*>(&As2[row * 40 + seg * 8]) = av;
        }
        #pragma unroll
        for (int it = 0; it < 8; ++it) {
            int idx = it * 256 + tid;           // 0..2047
            int c = (idx >> 7) * 2, px = idx & 127;
            const float* hp = high + (n * C_ + k0 + c) * PS_ + pxb + px;
            unsigned lo = f2bu(hp[0]);
            unsigned hi = f2bu(hp[PS_]);
            *reinterpret_cast<unsigned*>(&Bs[px * 40 + c]) = lo | (hi << 16);
        }
        __syncthreads();
        short8 a0 = *reinterpret_cast<const short8*>(&As[(wid * 32 + col) * 40 + quad * 8]);
        short8 a1 = *reinterpret_cast<const short8*>(&As[(wid * 32 + 16 + col) * 40 + quad * 8]);
        short8 a2;
        if (wid < 2)
            a2 = *reinterpret_cast<const short8*>(&As2[(wid * 16 + col) * 40 + quad * 8]);
        #pragma unroll
        for (int nt = 0; nt < 8; ++nt) {
            short8 b = *reinterpret_cast<const short8*>(&Bs[(nt * 16 + col) * 40 + quad * 8]);
            acc[0][nt] = __builtin_amdgcn_mfma_f32_16x16x32_bf16(a0, b, acc[0][nt], 0, 0, 0);
            acc[1][nt] = __builtin_amdgcn_mfma_f32_16x16x32_bf16(a1, b, acc[1][nt], 0, 0, 0);
            if (wid < 2)
                cacc[nt] = __builtin_amdgcn_mfma_f32_16x16x32_bf16(a2, b, cacc[nt], 0, 0, 0);
        }
    }
    #pragma unroll
    for (int mi = 0; mi < 2; ++mi) {
        int ob = o0 + wid * 32 + mi * 16 + quad * 4;
        #pragma unroll
        for (int nt = 0; nt < 8; ++nt) {
            int gpx = px0 + nt * 16 + col;
            unsigned lo = f2bu(acc[mi][nt][0]) | ((unsigned)f2bu(acc[mi][nt][1]) << 16);
            unsigned hi = f2bu(acc[mi][nt][2]) | ((unsigned)f2bu(acc[mi][nt][3]) << 16);
            uint2 pk; pk.x = lo; pk.y = hi;
            *reinterpret_cast<uint2*>(Yt + (size_t)gpx * 256 + ob) = pk;
        }
    }
    if (wid < 2) {
        #pragma unroll
        for (int r = 0; r < 4; ++r) {
            int m = y * 32 + wid * 16 + quad * 4 + r;
            float bias = b_cc[m];
            float* cp = comp + (size_t)(n * COMP_ + m) * PS_ + pxb + col;
            #pragma unroll
            for (int nt = 0; nt < 8; ++nt)
                cp[nt * 16] = cacc[nt][r] + bias;
        }
    }
}

// ---------------------------------------------------------------------------
// Kernel 2 (fused im2col + encoder GEMM + softmax): 256 blocks, one 8x8 tile
// each. Stages the 64ch x 10x10 comp halo in LDS (im2col's proven pattern),
// gathers B-fragments from it per K-step (no Icol round-trip). Halo buffer
// unioned with raw-mask buffer (both 6400 f32). Output msm TILE-MAJOR:
// msm[(n*64+tile)][q][64 px] f32, pre-softmaxed.
__global__ __launch_bounds__(256) void k_encode_mfma(const u16* __restrict__ Wb,
        const float* __restrict__ comp, const float* __restrict__ b_ce,
        float* __restrict__ msm) {
    int tid = threadIdx.x;
    int wid = tid >> 6, lane = tid & 63;
    int col = lane & 15, quad = lane >> 4;
    int b = blockIdx.x;
    int n = b >> 6, tile = b & 63;
    int ty0 = (tile >> 3) << 3, tx0 = (tile & 7) << 3;
    __shared__ u16 As[128 * 40];
    __shared__ u16 Bs[64 * 40];
    __shared__ float buf[6400];   // ct (halo) during K-loop; mt (raw mask) after

    // stage comp halo tile: 64 ch x 10x10 (zero-padded) — im2col's pattern
    for (int idx = tid; idx < 6400; idx += 256) {
        int cc = idx / 100, r = idx - cc * 100;
        int yy = ty0 - 1 + r / 10, xx = tx0 - 1 + (r % 10);
        float v = 0.f;
        if ((unsigned)yy < 64u && (unsigned)xx < 64u)
            v = comp[(n * COMP_ + cc) * PS_ + yy * 64 + xx];
        buf[idx] = v;
    }

    int row = tid >> 2, seg = tid & 3;          // B-staging role: px row, k seg
    int base = (row >> 3) * 10 + (row & 7);     // halo offset of this pixel
    f32x4 acc[2][4] = {};
    #pragma unroll 1
    for (int k0 = 0; k0 < 576; k0 += 32) {
        __syncthreads();
        #pragma unroll
        for (int it = 0; it < 2; ++it) {   // A: 128 rows x 4 segs
            int s = tid + it * 256;
            int arow = s >> 2, aseg = s & 3;
            short8 av = *reinterpret_cast<const short8*>(Wb + arow * 576 + k0 + aseg * 8);
            *reinterpret_cast<short8*>(&As[arow * 40 + aseg * 8]) = av;
        }
        {   // B: gather 8 values from halo (fused im2col), cvt to bf16
            short8 bv;
            #pragma unroll
            for (int j = 0; j < 8; ++j) {
                int u = k0 + seg * 8 + j;
                int cc = (int)((unsigned)u / 9u);
                int t = u - cc * 9;
                int t3 = (int)((unsigned)t / 3u);
                bv[j] = (short)f2bu(buf[cc * 100 + t3 * 10 + (t - t3 * 3) + base]);
            }
            *reinterpret_cast<short8*>(&Bs[row * 40 + seg * 8]) = bv;
        }
        __syncthreads();
        short8 a0 = *reinterpret_cast<const short8*>(&As[(wid * 32 + col) * 40 + quad * 8]);
        short8 a1 = *reinterpret_cast<const short8*>(&As[(wid * 32 + 16 + col) * 40 + quad * 8]);
        #pragma unroll
        for (int nt = 0; nt < 4; ++nt) {
            short8 bb = *reinterpret_cast<const short8*>(&Bs[(nt * 16 + col) * 40 + quad * 8]);
            acc[0][nt] = __builtin_amdgcn_mfma_f32_16x16x32_bf16(a0, bb, acc[0][nt], 0, 0, 0);
            acc[1][nt] = __builtin_amdgcn_mfma_f32_16x16x32_bf16(a1, bb, acc[1][nt], 0, 0, 0);
        }
    }
    // halo dead (all reads completed before final in-loop barrier);
    // reuse buf as raw-mask mt[q][64 px]
    #pragma unroll
    for (int mi = 0; mi < 2; ++mi) {
        int qbase = (wid * 2 + mi) * 16 + quad * 4;
        #pragma unroll
        for (int r = 0; r < 4; ++r) {
            int q = qbase + r;
            if (q < 100) {
                float bias = b_ce[q];
                #pragma unroll
                for (int nt = 0; nt < 4; ++nt)
                    buf[q * 64 + nt * 16 + col] = acc[mi][nt][r] + bias;
            }
        }
    }
    __syncthreads();
    // softmax over 25 taps for (px, sp); write tile-major contiguous
    {
        int px = tid & 63, sp = tid >> 6;
        float p[25];
        float mx = -1e30f;
        #pragma unroll
        for (int k = 0; k < 25; ++k) {
            p[k] = buf[(k * 4 + sp) * 64 + px];
            mx = fmaxf(mx, p[k]);
        }
        float sum = 0.f;
        #pragma unroll
        for (int k = 0; k < 25; ++k) { p[k] = __expf(p[k] - mx); sum += p[k]; }
        float inv = 1.f / sum;
        float* mo = msm + (size_t)b * 6400;
        #pragma unroll
        for (int k = 0; k < 25; ++k)
            mo[(k * 4 + sp) * 64 + px] = p[k] * inv;
    }
}

// ---------------------------------------------------------------------------
// Kernel 3: CARAFE reassembly — EXACT r6 structure (grid (64,4,2), 256 thr,
// pad 68, proven 31.5 MB fetch / 66 MB write, 61 us). Only change: mask
// staging reads the tile-major msm contiguously (sole block ownership).
__global__ __launch_bounds__(256) void k_carafe(const u16* __restrict__ Yt,
        const float* __restrict__ msm, const float* __restrict__ beff,
        float* __restrict__ xout, float* __restrict__ ps, float* __restrict__ pq) {
    int tile = blockIdx.x, n = blockIdx.y, half = blockIdx.z;
    int sh0 = (tile >> 3) << 3, sw0 = (tile & 7) << 3;
    int tid = threadIdx.x;
    int px = tid & 63, g = tid >> 6;
    int ly = px >> 3, lx = px & 7;
    int h = sh0 + ly, w = sw0 + lx;

    __shared__ float mt[6400];       // [q][64 px]   25.6 KB (pre-softmaxed)
    __shared__ u16 xt[144 * 68];     // [halo px][64 ch pad]  19.6 KB

    const float* msrc = msm + (size_t)(n * 64 + tile) * 6400;
    for (int idx = tid; idx < 6400; idx += 256)
        mt[idx] = msrc[idx];
    __syncthreads();

    // per-thread weights: plain LDS loads (softmax already applied upstream)
    float vs[4][25];
    #pragma unroll
    for (int s = 0; s < 4; ++s) {
        #pragma unroll
        for (int k = 0; k < 25; ++k) vs[s][k] = mt[(k * 4 + s) * 64 + px];
    }

    const u16* Yb = Yt + (size_t)n * PS_ * 256;
    float* hp_base = xout + (size_t)(n * C_) * PO_;
    int slotbase = ((n * 64 + tile) * 2 + half) * 128;   // block-owned 512-B seg
    #pragma unroll 1
    for (int chunk = 0; chunk < 2; ++chunk) {
        int ch0 = half * 128 + chunk * 64;
        __syncthreads();
        for (int idx = tid; idx < 1152; idx += 256) {
            int sp = idx >> 3, seg = idx & 7;
            int row = sp / 12, colm = sp - row * 12;
            int yy = sh0 - 2 + row, xx = sw0 - 2 + colm;
            short8 val = {};
            if ((unsigned)yy < 64u && (unsigned)xx < 64u)
                val = *reinterpret_cast<const short8*>(Yb + (size_t)(yy * 64 + xx) * 256 + ch0 + seg * 8);
            *reinterpret_cast<short8*>(&xt[sp * 68 + seg * 8]) = val;
        }
        __syncthreads();
        #pragma unroll 1
        for (int cq = 0; cq < 4; ++cq) {
            int c = g * 16 + cq * 4;        // within chunk
            int ch = ch0 + c;
            f32x4 bv = *reinterpret_cast<const f32x4*>(beff + ch);
            float a_[4][4];
            #pragma unroll
            for (int s = 0; s < 4; ++s) {
                a_[s][0] = bv[0]; a_[s][1] = bv[1]; a_[s][2] = bv[2]; a_[s][3] = bv[3];
            }
            const u16* bp = xt + (ly * 12 + lx) * 68 + c;
            #pragma unroll
            for (int ky = 0; ky < 5; ++ky) {
                #pragma unroll
                for (int kx = 0; kx < 5; ++kx) {
                    uint2 rv = *reinterpret_cast<const uint2*>(bp + (ky * 12 + kx) * 68);
                    float f0 = bits2f(rv.x << 16);
                    float f1 = bits2f(rv.x & 0xffff0000u);
                    float f2 = bits2f(rv.y << 16);
                    float f3 = bits2f(rv.y & 0xffff0000u);
                    int k = ky * 5 + kx;
                    #pragma unroll
                    for (int s = 0; s < 4; ++s) {
                        float m = vs[s][k];
                        a_[s][0] += m * f0; a_[s][1] += m * f1;
                        a_[s][2] += m * f2; a_[s][3] += m * f3;
                    }
                }
            }
            #pragma unroll
            for (int i = 0; i < 4; ++i) {
                float* op = hp_base + (size_t)(ch + i) * PO_ + (2 * h) * 128 + 2 * w;
                float2 r0; r0.x = a_[0][i]; r0.y = a_[1][i];
                float2 r1; r1.x = a_[2][i]; r1.y = a_[3][i];
                *reinterpret_cast<float2*>(op) = r0;
                *reinterpret_cast<float2*>(op + 128) = r1;
            }
            // BN partials: wave-reduce 64 px x 4 subpixels per channel
            f32x4 sv, qv;
            #pragma unroll
            for (int i = 0; i < 4; ++i) {
                float s  = a_[0][i] + a_[1][i] + a_[2][i] + a_[3][i];
                float q2 = a_[0][i] * a_[0][i] + a_[1][i] * a_[1][i]
                         + a_[2][i] * a_[2][i] + a_[3][i] * a_[3][i];
                #pragma unroll
                for (int off = 1; off < 64; off <<= 1) {
                    s  += __shfl_xor(s, off);
                    q2 += __shfl_xor(q2, off);
                }
                sv[i] = s; qv[i] = q2;
            }
            if ((tid & 63) == 0) {
                *reinterpret_cast<f32x4*>(ps + slotbase + chunk * 64 + c) = sv;
                *reinterpret_cast<f32x4*>(pq + slotbase + chunk * 64 + c) = qv;
            }
        }
    }
}

// ---------------------------------------------------------------------------
// Kernel 4 (merged stats+norm): block = (channel o, batch n). r6-verified.
__global__ __launch_bounds__(256) void k_bn(const float* __restrict__ ps,
        const float* __restrict__ pq, const float* __restrict__ gamma,
        const float* __restrict__ beta, float* __restrict__ xb) {
    int o = blockIdx.x >> 2, n = blockIdx.x & 3;
    int half = o >> 7, coff = o & 127;
    int tid = threadIdx.x;
    float s = ps[(tid * 2 + half) * 128 + coff];
    float q = pq[(tid * 2 + half) * 128 + coff];
    __shared__ float rs[256], rq[256];
    rs[tid] = s; rq[tid] = q;
    __syncthreads();
    for (int off = 128; off > 0; off >>= 1) {
        if (tid < off) { rs[tid] += rs[tid + off]; rq[tid] += rq[tid + off]; }
        __syncthreads();
    }
    __shared__ float sc_s, sh_s;
    if (tid == 0) {
        float mean = rs[0] * (1.f / 65536.f);
        float var  = rq[0] * (1.f / 65536.f) - mean * mean;
        float sc = rsqrtf(var + 1e-5f) * gamma[o];
        sc_s = sc;
        sh_s = beta[o] - mean * sc;
    }
    __syncthreads();
    float sc = sc_s, sh = sh_s;
    float* p = xb + (size_t)(n * C_ + o) * PO_;
    #pragma unroll 4
    for (int i = tid * 4; i < PO_; i += 1024) {
        float4 v = *reinterpret_cast<const float4*>(p + i);
        v.x = fmaxf(v.x * sc + sh, 0.f);
        v.y = fmaxf(v.y * sc + sh, 0.f);
        v.z = fmaxf(v.z * sc + sh, 0.f);
        v.w = fmaxf(v.w * sc + sh, 0.f);
        *reinterpret_cast<float4*>(p + i) = v;
    }
}

// ---------------------------------------------------------------------------
extern "C" void kernel_launch(void* const* d_in, const int* in_sizes, int n_in,
                              void* d_out, int out_size, void* d_ws, size_t ws_size,
                              hipStream_t stream) {
    const float* high    = (const float*)d_in[1];
    const float* w_cc    = (const float*)d_in[2];
    const float* b_cc    = (const float*)d_in[3];
    const float* w_ce    = (const float*)d_in[4];
    const float* b_ce    = (const float*)d_in[5];
    const float* w_conv2 = (const float*)d_in[6];
    const float* b_conv2 = (const float*)d_in[7];
    const float* w_bott  = (const float*)d_in[8];
    const float* gamma   = (const float*)d_in[9];
    const float* beta    = (const float*)d_in[10];

    char* ws = (char*)d_ws;
    float* beff    = (float*)(ws + 0);
    u16*   Weff_bf = (u16*)  (ws + 3072);        // 131072 B
    u16*   Wcc_bf  = (u16*)  (ws + 134144);      // 32768 B
    u16*   Wb      = (u16*)  (ws + 166912);      // 147456 B -> ends 314368
    float* comp    = (float*)(ws + 314368);      // 4 MB -> ends 4508672
    float* msm     = (float*)(ws + 4508672);     // 6.55 MB tile-major softmaxed mask
    u16*   Yt      = (u16*)  (ws + 11062272);    // 8.4 MB bf16 -> ends 19450880
    float* ps      = (float*)(ws + 19450880);    // 256 KB [512 slot][128 ch]
    float* pq      = (float*)(ws + 19713024);    // 256 KB -> ends 19975168
    float* xout    = (float*)d_out;              // pre-BN x, normalized in place

    k_prep        <<<608, 256, 0, stream>>>(w_bott, w_conv2, b_conv2, w_ce, w_cc,
                                            Weff_bf, beff, Wb, Wcc_bf);
    k_ygemm_fused <<<dim3(128, 2), 256, 0, stream>>>(Weff_bf, Wcc_bf, high, b_cc, Yt, comp);
    k_encode_mfma <<<256, 256, 0, stream>>>(Wb, comp, b_ce, msm);
    k_carafe      <<<dim3(64, 4, 2), 256, 0, stream>>>(Yt, msm, beff, xout, ps, pq);
    k_bn          <<<1024, 256, 0, stream>>>(ps, pq, gamma, beta, xout);
}

// Round 14
// 245.519 us; speedup vs baseline: 1.3445x; 1.0095x over previous
//
#include <hip/hip_runtime.h>
#include <hip/hip_bf16.h>

// Problem constants
#define N_    4
#define C_    256
#define PS_   4096      // 64*64 source pixels
#define PO_   16384     // 128*128 output pixels
#define COMP_ 64
#define QCH_  100       // K*K*R*R

typedef unsigned short u16;
typedef __attribute__((ext_vector_type(8))) short short8;   // 8 bf16 = 4 VGPR
typedef __attribute__((ext_vector_type(4))) float f32x4;

__device__ __forceinline__ u16 f2bu(float f) {
    __hip_bfloat16 h = __float2bfloat16(f);
    return __builtin_bit_cast(u16, h);
}
__device__ __forceinline__ float bits2f(unsigned u) {
    union { unsigned i; float f; } v; v.i = u; return v.f;
}

// ---------------------------------------------------------------------------
// Kernel 0 (merged prep):
//  bid<256 : Weff_bf[o][c] = bf16( w_bott[o,:256]@w_conv2 + w_bott[o,256+c] ), beff
//  bid<544 : Wb[128 q][576 u] bf16 (pad q 100->128)
//  else    : Wcc_bf[64 m][256 c] bf16
__global__ __launch_bounds__(256) void k_prep(const float* __restrict__ w_bott,
        const float* __restrict__ w_conv2, const float* __restrict__ b_conv2,
        const float* __restrict__ w_ce, const float* __restrict__ w_cc,
        u16* __restrict__ Weff_bf, float* __restrict__ beff,
        u16* __restrict__ Wb, u16* __restrict__ Wcc_bf) {
    int bid = blockIdx.x;
    if (bid < 256) {
        int o = bid, c = threadIdx.x;
        __shared__ float wb[512];
        wb[c]       = w_bott[o * 512 + c];
        wb[c + 256] = w_bott[o * 512 + 256 + c];
        __syncthreads();
        float acc = wb[256 + c];
        #pragma unroll 8
        for (int m = 0; m < 256; ++m)
            acc += wb[m] * w_conv2[m * 256 + c];
        Weff_bf[o * 256 + c] = f2bu(acc);
        if (c == 0) {
            float be = 0.f;
            for (int m = 0; m < 256; ++m) be += wb[m] * b_conv2[m];
            beff[o] = be;
        }
    } else if (bid < 544) {
        int i = (bid - 256) * 256 + threadIdx.x;   // over 128*576
        int q = i / 576, u = i - q * 576;
        float v = (q < 100) ? w_ce[q * 576 + u] : 0.f;
        Wb[i] = f2bu(v);
    } else {
        int j = (bid - 544) * 256 + threadIdx.x;   // over 64*256
        Wcc_bf[j] = f2bu(w_cc[j]);
    }
}

// ---------------------------------------------------------------------------
// Kernel 1 (fused Y GEMM + channel compressor): shares the B (high) staging.
// grid (128 px-blocks, 2 o-halves) — round-6 proven config.
// r14: B-staging via float2 loads (2 px/thread) — same bytes, half the loads.
__global__ __launch_bounds__(256) void k_ygemm_fused(const u16* __restrict__ Weff_bf,
        const u16* __restrict__ Wcc_bf, const float* __restrict__ high,
        const float* __restrict__ b_cc, u16* __restrict__ Yt,
        float* __restrict__ comp) {
    int tid = threadIdx.x;
    int wid = tid >> 6, lane = tid & 63;
    int col = lane & 15, quad = lane >> 4;
    int px0 = blockIdx.x * 128;
    int y = blockIdx.y;
    int o0 = y * 128;
    int n = px0 >> 12, pxb = px0 & 4095;
    __shared__ u16 As[128 * 40];
    __shared__ u16 As2[32 * 40];
    __shared__ u16 Bs[128 * 40];
    f32x4 acc[2][8] = {};
    f32x4 cacc[8] = {};
    #pragma unroll 1
    for (int k0 = 0; k0 < 256; k0 += 32) {
        __syncthreads();
        #pragma unroll
        for (int it = 0; it < 2; ++it) {
            int s = tid + it * 256;
            int row = s >> 2, seg = s & 3;
            short8 av = *reinterpret_cast<const short8*>(Weff_bf + (o0 + row) * 256 + k0 + seg * 8);
            *reinterpret_cast<short8*>(&As[row * 40 + seg * 8]) = av;
        }
        if (tid < 128) {   // comp weights: 32 rows
            int row = tid >> 2, seg = tid & 3;
            short8 av = *reinterpret_cast<const short8*>(Wcc_bf + (y * 32 + row) * 256 + k0 + seg * 8);
            *reinterpret_cast<short8*>(&As2[row * 40 + seg * 8]) = av;
        }
        #pragma unroll
        for (int it = 0; it < 4; ++it) {
            int idx = it * 256 + tid;           // 0..1023
            int c = (idx >> 6) * 2, px2 = (idx & 63) * 2;
            const float* hp = high + (n * C_ + k0 + c) * PS_ + pxb + px2;
            float2 v0 = *reinterpret_cast<const float2*>(hp);
            float2 v1 = *reinterpret_cast<const float2*>(hp + PS_);
            *reinterpret_cast<unsigned*>(&Bs[px2 * 40 + c]) =
                (unsigned)f2bu(v0.x) | ((unsigned)f2bu(v1.x) << 16);
            *reinterpret_cast<unsigned*>(&Bs[(px2 + 1) * 40 + c]) =
                (unsigned)f2bu(v0.y) | ((unsigned)f2bu(v1.y) << 16);
        }
        __syncthreads();
        short8 a0 = *reinterpret_cast<const short8*>(&As[(wid * 32 + col) * 40 + quad * 8]);
        short8 a1 = *reinterpret_cast<const short8*>(&As[(wid * 32 + 16 + col) * 40 + quad * 8]);
        short8 a2;
        if (wid < 2)
            a2 = *reinterpret_cast<const short8*>(&As2[(wid * 16 + col) * 40 + quad * 8]);
        #pragma unroll
        for (int nt = 0; nt < 8; ++nt) {
            short8 b = *reinterpret_cast<const short8*>(&Bs[(nt * 16 + col) * 40 + quad * 8]);
            acc[0][nt] = __builtin_amdgcn_mfma_f32_16x16x32_bf16(a0, b, acc[0][nt], 0, 0, 0);
            acc[1][nt] = __builtin_amdgcn_mfma_f32_16x16x32_bf16(a1, b, acc[1][nt], 0, 0, 0);
            if (wid < 2)
                cacc[nt] = __builtin_amdgcn_mfma_f32_16x16x32_bf16(a2, b, cacc[nt], 0, 0, 0);
        }
    }
    #pragma unroll
    for (int mi = 0; mi < 2; ++mi) {
        int ob = o0 + wid * 32 + mi * 16 + quad * 4;
        #pragma unroll
        for (int nt = 0; nt < 8; ++nt) {
            int gpx = px0 + nt * 16 + col;
            unsigned lo = f2bu(acc[mi][nt][0]) | ((unsigned)f2bu(acc[mi][nt][1]) << 16);
            unsigned hi = f2bu(acc[mi][nt][2]) | ((unsigned)f2bu(acc[mi][nt][3]) << 16);
            uint2 pk; pk.x = lo; pk.y = hi;
            *reinterpret_cast<uint2*>(Yt + (size_t)gpx * 256 + ob) = pk;
        }
    }
    if (wid < 2) {
        #pragma unroll
        for (int r = 0; r < 4; ++r) {
            int m = y * 32 + wid * 16 + quad * 4 + r;
            float bias = b_cc[m];
            float* cp = comp + (size_t)(n * COMP_ + m) * PS_ + pxb + col;
            #pragma unroll
            for (int nt = 0; nt < 8; ++nt)
                cp[nt * 16] = cacc[nt][r] + bias;
        }
    }
}

// ---------------------------------------------------------------------------
// Kernel 2 (fused im2col + encoder GEMM + softmax): 256 blocks, one 8x8 tile
// each. Stages the 64ch x 10x10 comp halo in LDS, gathers B-fragments from it
// per K-step. r14: gather offsets precomputed in a 576-entry LDS table
// (replaces the per-element div/mul chains). Output msm TILE-MAJOR.
__global__ __launch_bounds__(256) void k_encode_mfma(const u16* __restrict__ Wb,
        const float* __restrict__ comp, const float* __restrict__ b_ce,
        float* __restrict__ msm) {
    int tid = threadIdx.x;
    int wid = tid >> 6, lane = tid & 63;
    int col = lane & 15, quad = lane >> 4;
    int b = blockIdx.x;
    int n = b >> 6, tile = b & 63;
    int ty0 = (tile >> 3) << 3, tx0 = (tile & 7) << 3;
    __shared__ u16 As[128 * 40];
    __shared__ u16 Bs[64 * 40];
    __shared__ float buf[6400];     // ct (halo) during K-loop; mt (raw mask) after
    __shared__ u16 off_tab[576];    // u -> halo offset (cc*100 + ky*10 + kx)

    // stage comp halo tile: 64 ch x 10x10 (zero-padded) — im2col's pattern
    for (int idx = tid; idx < 6400; idx += 256) {
        int cc = idx / 100, r = idx - cc * 100;
        int yy = ty0 - 1 + r / 10, xx = tx0 - 1 + (r % 10);
        float v = 0.f;
        if ((unsigned)yy < 64u && (unsigned)xx < 64u)
            v = comp[(n * COMP_ + cc) * PS_ + yy * 64 + xx];
        buf[idx] = v;
    }
    // offset table (once per block)
    for (int u = tid; u < 576; u += 256) {
        int cc = (int)((unsigned)u / 9u);
        int t = u - cc * 9;
        int t3 = (int)((unsigned)t / 3u);
        off_tab[u] = (u16)(cc * 100 + t3 * 10 + (t - t3 * 3));
    }

    int row = tid >> 2, seg = tid & 3;          // B-staging role: px row, k seg
    int base = (row >> 3) * 10 + (row & 7);     // halo offset of this pixel
    f32x4 acc[2][4] = {};
    #pragma unroll 1
    for (int k0 = 0; k0 < 576; k0 += 32) {
        __syncthreads();
        #pragma unroll
        for (int it = 0; it < 2; ++it) {   // A: 128 rows x 4 segs
            int s = tid + it * 256;
            int arow = s >> 2, aseg = s & 3;
            short8 av = *reinterpret_cast<const short8*>(Wb + arow * 576 + k0 + aseg * 8);
            *reinterpret_cast<short8*>(&As[arow * 40 + aseg * 8]) = av;
        }
        {   // B: gather 8 values from halo via offset table, cvt to bf16
            short8 bv;
            #pragma unroll
            for (int j = 0; j < 8; ++j)
                bv[j] = (short)f2bu(buf[off_tab[k0 + seg * 8 + j] + base]);
            *reinterpret_cast<short8*>(&Bs[row * 40 + seg * 8]) = bv;
        }
        __syncthreads();
        short8 a0 = *reinterpret_cast<const short8*>(&As[(wid * 32 + col) * 40 + quad * 8]);
        short8 a1 = *reinterpret_cast<const short8*>(&As[(wid * 32 + 16 + col) * 40 + quad * 8]);
        #pragma unroll
        for (int nt = 0; nt < 4; ++nt) {
            short8 bb = *reinterpret_cast<const short8*>(&Bs[(nt * 16 + col) * 40 + quad * 8]);
            acc[0][nt] = __builtin_amdgcn_mfma_f32_16x16x32_bf16(a0, bb, acc[0][nt], 0, 0, 0);
            acc[1][nt] = __builtin_amdgcn_mfma_f32_16x16x32_bf16(a1, bb, acc[1][nt], 0, 0, 0);
        }
    }
    // halo dead; reuse buf as raw-mask mt[q][64 px]
    #pragma unroll
    for (int mi = 0; mi < 2; ++mi) {
        int qbase = (wid * 2 + mi) * 16 + quad * 4;
        #pragma unroll
        for (int r = 0; r < 4; ++r) {
            int q = qbase + r;
            if (q < 100) {
                float bias = b_ce[q];
                #pragma unroll
                for (int nt = 0; nt < 4; ++nt)
                    buf[q * 64 + nt * 16 + col] = acc[mi][nt][r] + bias;
            }
        }
    }
    __syncthreads();
    // softmax over 25 taps for (px, sp); write tile-major contiguous
    {
        int px = tid & 63, sp = tid >> 6;
        float p[25];
        float mx = -1e30f;
        #pragma unroll
        for (int k = 0; k < 25; ++k) {
            p[k] = buf[(k * 4 + sp) * 64 + px];
            mx = fmaxf(mx, p[k]);
        }
        float sum = 0.f;
        #pragma unroll
        for (int k = 0; k < 25; ++k) { p[k] = __expf(p[k] - mx); sum += p[k]; }
        float inv = 1.f / sum;
        float* mo = msm + (size_t)b * 6400;
        #pragma unroll
        for (int k = 0; k < 25; ++k)
            mo[(k * 4 + sp) * 64 + px] = p[k] * inv;
    }
}

// ---------------------------------------------------------------------------
// Kernel 3: CARAFE reassembly — EXACT r13 kernel (frozen; 46.5 us, 12.4 MB
// fetch / 66 MB write measured). Tile-major contiguous mask staging.
__global__ __launch_bounds__(256) void k_carafe(const u16* __restrict__ Yt,
        const float* __restrict__ msm, const float* __restrict__ beff,
        float* __restrict__ xout, float* __restrict__ ps, float* __restrict__ pq) {
    int tile = blockIdx.x, n = blockIdx.y, half = blockIdx.z;
    int sh0 = (tile >> 3) << 3, sw0 = (tile & 7) << 3;
    int tid = threadIdx.x;
    int px = tid & 63, g = tid >> 6;
    int ly = px >> 3, lx = px & 7;
    int h = sh0 + ly, w = sw0 + lx;

    __shared__ float mt[6400];       // [q][64 px]   25.6 KB (pre-softmaxed)
    __shared__ u16 xt[144 * 68];     // [halo px][64 ch pad]  19.6 KB

    const float* msrc = msm + (size_t)(n * 64 + tile) * 6400;
    for (int idx = tid; idx < 6400; idx += 256)
        mt[idx] = msrc[idx];
    __syncthreads();

    // per-thread weights: plain LDS loads (softmax already applied upstream)
    float vs[4][25];
    #pragma unroll
    for (int s = 0; s < 4; ++s) {
        #pragma unroll
        for (int k = 0; k < 25; ++k) vs[s][k] = mt[(k * 4 + s) * 64 + px];
    }

    const u16* Yb = Yt + (size_t)n * PS_ * 256;
    float* hp_base = xout + (size_t)(n * C_) * PO_;
    int slotbase = ((n * 64 + tile) * 2 + half) * 128;   // block-owned 512-B seg
    #pragma unroll 1
    for (int chunk = 0; chunk < 2; ++chunk) {
        int ch0 = half * 128 + chunk * 64;
        __syncthreads();
        for (int idx = tid; idx < 1152; idx += 256) {
            int sp = idx >> 3, seg = idx & 7;
            int row = sp / 12, colm = sp - row * 12;
            int yy = sh0 - 2 + row, xx = sw0 - 2 + colm;
            short8 val = {};
            if ((unsigned)yy < 64u && (unsigned)xx < 64u)
                val = *reinterpret_cast<const short8*>(Yb + (size_t)(yy * 64 + xx) * 256 + ch0 + seg * 8);
            *reinterpret_cast<short8*>(&xt[sp * 68 + seg * 8]) = val;
        }
        __syncthreads();
        #pragma unroll 1
        for (int cq = 0; cq < 4; ++cq) {
            int c = g * 16 + cq * 4;        // within chunk
            int ch = ch0 + c;
            f32x4 bv = *reinterpret_cast<const f32x4*>(beff + ch);
            float a_[4][4];
            #pragma unroll
            for (int s = 0; s < 4; ++s) {
                a_[s][0] = bv[0]; a_[s][1] = bv[1]; a_[s][2] = bv[2]; a_[s][3] = bv[3];
            }
            const u16* bp = xt + (ly * 12 + lx) * 68 + c;
            #pragma unroll
            for (int ky = 0; ky < 5; ++ky) {
                #pragma unroll
                for (int kx = 0; kx < 5; ++kx) {
                    uint2 rv = *reinterpret_cast<const uint2*>(bp + (ky * 12 + kx) * 68);
                    float f0 = bits2f(rv.x << 16);
                    float f1 = bits2f(rv.x & 0xffff0000u);
                    float f2 = bits2f(rv.y << 16);
                    float f3 = bits2f(rv.y & 0xffff0000u);
                    int k = ky * 5 + kx;
                    #pragma unroll
                    for (int s = 0; s < 4; ++s) {
                        float m = vs[s][k];
                        a_[s][0] += m * f0; a_[s][1] += m * f1;
                        a_[s][2] += m * f2; a_[s][3] += m * f3;
                    }
                }
            }
            #pragma unroll
            for (int i = 0; i < 4; ++i) {
                float* op = hp_base + (size_t)(ch + i) * PO_ + (2 * h) * 128 + 2 * w;
                float2 r0; r0.x = a_[0][i]; r0.y = a_[1][i];
                float2 r1; r1.x = a_[2][i]; r1.y = a_[3][i];
                *reinterpret_cast<float2*>(op) = r0;
                *reinterpret_cast<float2*>(op + 128) = r1;
            }
            // BN partials: wave-reduce 64 px x 4 subpixels per channel
            f32x4 sv, qv;
            #pragma unroll
            for (int i = 0; i < 4; ++i) {
                float s  = a_[0][i] + a_[1][i] + a_[2][i] + a_[3][i];
                float q2 = a_[0][i] * a_[0][i] + a_[1][i] * a_[1][i]
                         + a_[2][i] * a_[2][i] + a_[3][i] * a_[3][i];
                #pragma unroll
                for (int off = 1; off < 64; off <<= 1) {
                    s  += __shfl_xor(s, off);
                    q2 += __shfl_xor(q2, off);
                }
                sv[i] = s; qv[i] = q2;
            }
            if ((tid & 63) == 0) {
                *reinterpret_cast<f32x4*>(ps + slotbase + chunk * 64 + c) = sv;
                *reinterpret_cast<f32x4*>(pq + slotbase + chunk * 64 + c) = qv;
            }
        }
    }
}

// ---------------------------------------------------------------------------
// Kernel 4 (merged stats+norm): block = (channel o, batch n). r6-verified.
__global__ __launch_bounds__(256) void k_bn(const float* __restrict__ ps,
        const float* __restrict__ pq, const float* __restrict__ gamma,
        const float* __restrict__ beta, float* __restrict__ xb) {
    int o = blockIdx.x >> 2, n = blockIdx.x & 3;
    int half = o >> 7, coff = o & 127;
    int tid = threadIdx.x;
    float s = ps[(tid * 2 + half) * 128 + coff];
    float q = pq[(tid * 2 + half) * 128 + coff];
    __shared__ float rs[256], rq[256];
    rs[tid] = s; rq[tid] = q;
    __syncthreads();
    for (int off = 128; off > 0; off >>= 1) {
        if (tid < off) { rs[tid] += rs[tid + off]; rq[tid] += rq[tid + off]; }
        __syncthreads();
    }
    __shared__ float sc_s, sh_s;
    if (tid == 0) {
        float mean = rs[0] * (1.f / 65536.f);
        float var  = rq[0] * (1.f / 65536.f) - mean * mean;
        float sc = rsqrtf(var + 1e-5f) * gamma[o];
        sc_s = sc;
        sh_s = beta[o] - mean * sc;
    }
    __syncthreads();
    float sc = sc_s, sh = sh_s;
    float* p = xb + (size_t)(n * C_ + o) * PO_;
    #pragma unroll 4
    for (int i = tid * 4; i < PO_; i += 1024) {
        float4 v = *reinterpret_cast<const float4*>(p + i);
        v.x = fmaxf(v.x * sc + sh, 0.f);
        v.y = fmaxf(v.y * sc + sh, 0.f);
        v.z = fmaxf(v.z * sc + sh, 0.f);
        v.w = fmaxf(v.w * sc + sh, 0.f);
        *reinterpret_cast<float4*>(p + i) = v;
    }
}

// ---------------------------------------------------------------------------
extern "C" void kernel_launch(void* const* d_in, const int* in_sizes, int n_in,
                              void* d_out, int out_size, void* d_ws, size_t ws_size,
                              hipStream_t stream) {
    const float* high    = (const float*)d_in[1];
    const float* w_cc    = (const float*)d_in[2];
    const float* b_cc    = (const float*)d_in[3];
    const float* w_ce    = (const float*)d_in[4];
    const float* b_ce    = (const float*)d_in[5];
    const float* w_conv2 = (const float*)d_in[6];
    const float* b_conv2 = (const float*)d_in[7];
    const float* w_bott  = (const float*)d_in[8];
    const float* gamma   = (const float*)d_in[9];
    const float* beta    = (const float*)d_in[10];

    char* ws = (char*)d_ws;
    float* beff    = (float*)(ws + 0);
    u16*   Weff_bf = (u16*)  (ws + 3072);        // 131072 B
    u16*   Wcc_bf  = (u16*)  (ws + 134144);      // 32768 B
    u16*   Wb      = (u16*)  (ws + 166912);      // 147456 B -> ends 314368
    float* comp    = (float*)(ws + 314368);      // 4 MB -> ends 4508672
    float* msm     = (float*)(ws + 4508672);     // 6.55 MB tile-major softmaxed mask
    u16*   Yt      = (u16*)  (ws + 11062272);    // 8.4 MB bf16 -> ends 19450880
    float* ps      = (float*)(ws + 19450880);    // 256 KB [512 slot][128 ch]
    float* pq      = (float*)(ws + 19713024);    // 256 KB -> ends 19975168
    float* xout    = (float*)d_out;              // pre-BN x, normalized in place

    k_prep        <<<608, 256, 0, stream>>>(w_bott, w_conv2, b_conv2, w_ce, w_cc,
                                            Weff_bf, beff, Wb, Wcc_bf);
    k_ygemm_fused <<<dim3(128, 2), 256, 0, stream>>>(Weff_bf, Wcc_bf, high, b_cc, Yt, comp);
    k_encode_mfma <<<256, 256, 0, stream>>>(Wb, comp, b_ce, msm);
    k_carafe      <<<dim3(64, 4, 2), 256, 0, stream>>>(Yt, msm, beff, xout, ps, pq);
    k_bn          <<<1024, 256, 0, stream>>>(ps, pq, gamma, beta, xout);
}